// Round 7
// baseline (441.011 us; speedup 1.0000x reference)
//
#include <hip/hip_runtime.h>

#define BB 128
#define SS 64
#define KK 10
#define DD 256
#define NN (BB*SS)        // 8192 rows
#define ROWS 32           // rows per block
#define NBLK (NN/ROWS)    // 256 blocks = 1 per CU
#define NT 1024           // 16 waves per block -> 4 waves/SIMD

typedef __attribute__((ext_vector_type(8))) short short8;
typedef __attribute__((ext_vector_type(4))) float f32x4;
typedef __attribute__((ext_vector_type(4))) unsigned uint4v;

#define FRAG_ELEMS (48*8*64*8)   // 196608 bf16 values per weight matrix

__device__ __forceinline__ unsigned short f2bf(float f){
  union { float f; unsigned u; } v; v.f = f;
  unsigned r = (v.u + 0x7FFFu + ((v.u >> 16) & 1u)) >> 16;
  return (unsigned short)r;
}

// packed RNE f32->bf16 pair: bits[15:0]=bf16(lo), [31:16]=bf16(hi).
// Identical rounding to f2bf on finite values (both RNE).
__device__ __forceinline__ unsigned cvtpk(float lo, float hi){
  unsigned r;
  asm("v_cvt_pk_bf16_f32 %0, %1, %2" : "=v"(r) : "v"(lo), "v"(hi));
  return r;
}

// Pre-swizzle W_ih[:, :D] and W_hh into bf16 MFMA B-fragment order:
// frag value at (tn, tk, lane, j) = W[c = tn*16 + (lane&15)][d = tk*32 + (lane>>4)*8 + j]
// stored flat at ((tn*8+tk)*64 + lane)*8 + j.  FW1 first, FWhh second.
__global__ void prep_weights(const float* __restrict__ Wih,
                             const float* __restrict__ Whh,
                             unsigned short* __restrict__ fw){
  int id = blockIdx.x * 256 + threadIdx.x;     // 0 .. 2*FRAG_ELEMS-1
  int arr = (id >= FRAG_ELEMS);
  int r = arr ? (id - FRAG_ELEMS) : id;
  int j  = r & 7;
  int l  = (r >> 3) & 63;
  int tk = (r >> 9) & 7;
  int tn = r >> 12;                            // 0..47
  int c  = tn * 16 + (l & 15);                 // 0..767
  int d  = tk * 32 + ((l >> 4) << 3) + j;      // 0..255
  float v = arr ? Whh[c * 256 + d] : Wih[c * 512 + d];
  fw[id] = f2bf(v);
}

// Baseline geometry (proven): 256 blocks x 1024 thr, 4 waves/SIMD, 128-reg
// unified budget/wave. r6 used 92 (60 arch + 32 acc) -> 36 headroom.
// This round: (1) full-unroll tk with literal offsets (no skew) so weight
// loads fold to base+imm and schedule early; (2) 6-fragment (24-reg)
// cross-barrier prime of tk=0 weights -- the only phase with zero loads in
// flight was the post-barrier cold start; (3) cvt_pk for x-staging.
// Spill signature to watch: FETCH >> 44 MB => revert the prime.
__global__ __launch_bounds__(NT, 4) void gru_main(
    const float* __restrict__ item, const float* __restrict__ user,
    const float* __restrict__ b_ih, const float* __restrict__ b_hh,
    const float* __restrict__ w_out, const float* __restrict__ b_out,
    const int* __restrict__ length, const unsigned short* __restrict__ ws,
    float* __restrict__ out)
{
  // A-fragment layout: elem (mt, tk, lane, j) at ((mt*8+tk)*64+lane)*8+j
  // double-buffered so one barrier/step suffices
  __shared__ unsigned short xfrag[2][2*8*64*8];   // 32 KB
  __shared__ unsigned short hfrag[2][2*8*64*8];   // 32 KB
  __shared__ float yp[3][16][2][4][4];            // 6 KB, triple-buffered

  const int tid  = threadIdx.x;
  const int lane = tid & 63;
  const int w    = tid >> 6;        // wave 0..15 == column group g
  const int col  = lane & 15;       // C-layout col
  const int q    = lane >> 4;       // quad
  const int nb   = blockIdx.x * ROWS;
  const int b    = nb / SS;         // one user per block (32 | 64)

  const short8* fw1 = (const short8*)ws;
  const short8* fwh = fw1 + (FRAG_ELEMS/8);

  // per-column constants (this thread owns output channel d for 8 rows)
  const int d    = w*16 + col;
  const float br_  = b_ih[d]       + b_hh[d];
  const float bz_  = b_ih[256 + d] + b_hh[256 + d];
  const float bin_ = b_ih[512 + d];
  const float bhn_ = b_hh[512 + d];
  const float wo_  = w_out[d];

  // weight fragment flat offsets (short8 units): frag(tn,tk) = fw[tn*512 + tk*64 + lane]
  const int wq0 = (w     )*512 + lane;   // gate r
  const int wq1 = (16 + w)*512 + lane;   // gate z
  const int wq2 = (32 + w)*512 + lane;   // gate n

  // h0 = user_embs[b, clip(length[b]-1,0)]; identical for all 32 rows
  int idx = length[b] - 1; if (idx < 0) idx = 0;
  const float u0 = user[((size_t)b*SS + idx)*DD + d];
  float h[2][4];
  #pragma unroll
  for (int mt = 0; mt < 2; ++mt)
    #pragma unroll
    for (int reg = 0; reg < 4; ++reg)
      h[mt][reg] = u0;

  // write h0 into hfrag[0] (A-fragment layout), owner-thread scatter
  const int tkk = d >> 5;
  const int slb = ((d >> 3) & 3) * 16;
  const int dj  = d & 7;
  {
    unsigned short hb = f2bf(u0);
    #pragma unroll
    for (int mt = 0; mt < 2; ++mt)
      #pragma unroll
      for (int reg = 0; reg < 4; ++reg)
        hfrag[0][((mt*8 + tkk)*64 + slb + q*4 + reg)*8 + dj] = hb;
  }

  // cooperative x-tile load: thread covers row = tid>>5, 8 d's at (tid&31)*8
  const int xrow = tid >> 5;        // 0..31
  const int xo   = tid & 31;        // which 8-wide d chunk
  const int xmt  = xrow >> 4;
  const int xtk  = xo >> 2;
  const int xsl  = (xo & 3)*16 + (xrow & 15);
  {
    const float4* p = (const float4*)(item + ((size_t)(nb + xrow)*KK + 0)*DD + xo*8);
    float4 a0 = p[0], a1 = p[1];
    uint4v t;
    t.x = cvtpk(a0.x, a0.y); t.y = cvtpk(a0.z, a0.w);
    t.z = cvtpk(a1.x, a1.y); t.w = cvtpk(a1.z, a1.w);
    *(uint4v*)&xfrag[0][((xmt*8 + xtk)*64 + xsl)*8] = t;
  }

  // prime tk=0 weight fragments (live across the barrier; 24 regs)
  short8 pw0 = fw1[wq0], pw1 = fw1[wq1], pw2 = fw1[wq2];
  short8 ph0 = fwh[wq0], ph1 = fwh[wq1], ph2 = fwh[wq2];

  __syncthreads();

  const float bout = b_out[0];

#define MFMA16(A,Bv,C) __builtin_amdgcn_mfma_f32_16x16x32_bf16(A,Bv,C,0,0,0)

  for (int k = 0; k < KK; ++k){
    const int cb  = k & 1;
    const int nbf = cb ^ 1;

    // accumulators: [mt][kind]  kind: 0=r 1=z 2=i_n 3=h_n
    f32x4 acc[2][4];
    #pragma unroll
    for (int mt = 0; mt < 2; ++mt)
      #pragma unroll
      for (int kd = 0; kd < 4; ++kd){
        f32x4 z4 = {0.f, 0.f, 0.f, 0.f};
        acc[mt][kd] = z4;
      }

    // next x tile issued up-front: latency hides under the whole MFMA phase
    float4 xn0, xn1;
    if (k < KK-1){
      const float4* p = (const float4*)(item + ((size_t)(nb + xrow)*KK + (k+1))*DD + xo*8);
      xn0 = p[0]; xn1 = p[1];
    }

    // fully-unrolled tk loop: all weight offsets are compile-time literals
    // (tk*1024 B fits the 13-bit imm field) -> minimal addr VALU, compiler
    // pipelines next-tk loads under current MFMAs within the 128-reg budget.
    #pragma unroll
    for (int tk = 0; tk < 8; ++tk){
      const int o_ = tk * 64;
      short8 w1r, w1z, w1n, whr, whz, whn;
      if (tk == 0){ w1r = pw0; w1z = pw1; w1n = pw2; whr = ph0; whz = ph1; whn = ph2; }
      else {
        w1r = fw1[wq0+o_]; w1z = fw1[wq1+o_]; w1n = fw1[wq2+o_];
        whr = fwh[wq0+o_]; whz = fwh[wq1+o_]; whn = fwh[wq2+o_];
      }
      short8 ax0 = *(const short8*)&xfrag[cb][((    tk)*64 + lane)*8];
      short8 ax1 = *(const short8*)&xfrag[cb][((8 + tk)*64 + lane)*8];
      short8 ah0 = *(const short8*)&hfrag[cb][((    tk)*64 + lane)*8];
      short8 ah1 = *(const short8*)&hfrag[cb][((8 + tk)*64 + lane)*8];
      __builtin_amdgcn_s_setprio(1);
      acc[0][0] = MFMA16(ax0, w1r, acc[0][0]);
      acc[0][0] = MFMA16(ah0, whr, acc[0][0]);
      acc[0][1] = MFMA16(ax0, w1z, acc[0][1]);
      acc[0][1] = MFMA16(ah0, whz, acc[0][1]);
      acc[0][2] = MFMA16(ax0, w1n, acc[0][2]);
      acc[0][3] = MFMA16(ah0, whn, acc[0][3]);
      acc[1][0] = MFMA16(ax1, w1r, acc[1][0]);
      acc[1][0] = MFMA16(ah1, whr, acc[1][0]);
      acc[1][1] = MFMA16(ax1, w1z, acc[1][1]);
      acc[1][1] = MFMA16(ah1, whz, acc[1][1]);
      acc[1][2] = MFMA16(ax1, w1n, acc[1][2]);
      acc[1][3] = MFMA16(ah1, whn, acc[1][3]);
      __builtin_amdgcn_s_setprio(0);
    }

    // gates — entirely in-register (v_rcp + v_med3; verified same absmax)
    float ypl[2][4];
    #pragma unroll
    for (int mt = 0; mt < 2; ++mt)
      #pragma unroll
      for (int reg = 0; reg < 4; ++reg){
        float rp = acc[mt][0][reg] + br_;
        float zp = acc[mt][1][reg] + bz_;
        float r  = __builtin_amdgcn_rcpf(1.f + __expf(-rp));
        float z  = __builtin_amdgcn_rcpf(1.f + __expf(-zp));
        float np = acc[mt][2][reg] + bin_ + r*(acc[mt][3][reg] + bhn_);
        np = __builtin_amdgcn_fmed3f(np, -30.f, 30.f);
        float e  = __expf(2.f*np);
        float n  = 1.f - 2.f*__builtin_amdgcn_rcpf(e + 1.f);   // tanh(np)
        float hv = (1.f - z)*n + z*h[mt][reg];
        h[mt][reg] = hv;
        ypl[mt][reg] = hv * wo_;
      }

    // y partial: reduce across the 16 cols of this wave's group
    #pragma unroll
    for (int mt = 0; mt < 2; ++mt)
      #pragma unroll
      for (int reg = 0; reg < 4; ++reg){
        float p = ypl[mt][reg];
        p += __shfl_xor(p, 1);
        p += __shfl_xor(p, 2);
        p += __shfl_xor(p, 4);
        p += __shfl_xor(p, 8);
        if (col == 0) yp[k % 3][w][mt][q][reg] = p;
      }

    // write h' (bf16) into hfrag[nbf] for next step
    #pragma unroll
    for (int mt = 0; mt < 2; ++mt)
      #pragma unroll
      for (int reg = 0; reg < 4; ++reg)
        hfrag[nbf][((mt*8 + tkk)*64 + slb + q*4 + reg)*8 + dj] = f2bf(h[mt][reg]);

    // write next x tile into xfrag[nbf]
    if (k < KK-1){
      uint4v t;
      t.x = cvtpk(xn0.x, xn0.y); t.y = cvtpk(xn0.z, xn0.w);
      t.z = cvtpk(xn1.x, xn1.y); t.w = cvtpk(xn1.z, xn1.w);
      *(uint4v*)&xfrag[nbf][((xmt*8 + xtk)*64 + xsl)*8] = t;
    }

    // re-prime tk=0 weights for the next step (addresses k-invariant; loads
    // fly through the yp-finalize, barrier, and next step's prologue)
    pw0 = fw1[wq0]; pw1 = fw1[wq1]; pw2 = fw1[wq2];
    ph0 = fwh[wq0]; ph1 = fwh[wq1]; ph2 = fwh[wq2];

    // finalize y for step k-1 (yp[(k-1)%3] stable since previous barrier;
    // concurrent writes go to yp[k%3] which is a different buffer)
    if (k > 0 && tid < 32){
      float s = bout;
      #pragma unroll
      for (int ww = 0; ww < 16; ++ww)
        s += yp[(k-1) % 3][ww][tid >> 4][(tid >> 2) & 3][tid & 3];
      out[(size_t)(nb + tid)*KK + (k-1)] = s;
    }

    __syncthreads();   // single barrier per step
  }

  // finalize y for the last step
  if (tid < 32){
    float s = bout;
    #pragma unroll
    for (int ww = 0; ww < 16; ++ww)
      s += yp[(KK-1) % 3][ww][tid >> 4][(tid >> 2) & 3][tid & 3];
    out[(size_t)(nb + tid)*KK + (KK-1)] = s;
  }
}

extern "C" void kernel_launch(void* const* d_in, const int* in_sizes, int n_in,
                              void* d_out, int out_size, void* d_ws, size_t ws_size,
                              hipStream_t stream) {
  const float* item   = (const float*)d_in[0];
  const float* user   = (const float*)d_in[1];
  const float* W_ih   = (const float*)d_in[2];
  const float* W_hh   = (const float*)d_in[3];
  const float* b_ih   = (const float*)d_in[4];
  const float* b_hh   = (const float*)d_in[5];
  const float* w_out  = (const float*)d_in[6];
  const float* b_out  = (const float*)d_in[7];
  const int*   length = (const int*)d_in[8];
  unsigned short* ws  = (unsigned short*)d_ws;   // needs 768 KB
  float* out = (float*)d_out;

  hipLaunchKernelGGL(prep_weights, dim3((2*FRAG_ELEMS)/256), dim3(256), 0, stream,
                     W_ih, W_hh, ws);
  hipLaunchKernelGGL(gru_main, dim3(NBLK), dim3(NT), 0, stream,
                     item, user, b_ih, b_hh, w_out, b_out, length, ws, out);
}

// Round 8
// 220.355 us; speedup vs baseline: 2.0014x; 2.0014x over previous
//
#include <hip/hip_runtime.h>

#define BB 128
#define SS 64
#define KK 10
#define DD 256
#define NN (BB*SS)        // 8192 rows
#define ROWS 32           // rows per block
#define NBLK (NN/ROWS)    // 256 blocks = 1 per CU
#define NT 1024           // 16 waves per block -> 4 waves/SIMD

typedef __attribute__((ext_vector_type(8))) short short8;
typedef __attribute__((ext_vector_type(4))) float f32x4;
typedef __attribute__((ext_vector_type(4))) unsigned uint4v;

#define FRAG_ELEMS (48*8*64*8)   // 196608 bf16 values per weight matrix

__device__ __forceinline__ unsigned short f2bf(float f){
  union { float f; unsigned u; } v; v.f = f;
  unsigned r = (v.u + 0x7FFFu + ((v.u >> 16) & 1u)) >> 16;
  return (unsigned short)r;
}

// packed RNE f32->bf16 pair: bits[15:0]=bf16(lo), [31:16]=bf16(hi).
// Same rounding as f2bf on finite values (both RNE). No builtin on gfx950.
__device__ __forceinline__ unsigned cvtpk(float lo, float hi){
  unsigned r;
  asm("v_cvt_pk_bf16_f32 %0, %1, %2" : "=v"(r) : "v"(lo), "v"(hi));
  return r;
}

// Pre-swizzle W_ih[:, :D] and W_hh into bf16 MFMA B-fragment order:
// frag value at (tn, tk, lane, j) = W[c = tn*16 + (lane&15)][d = tk*32 + (lane>>4)*8 + j]
// stored flat at ((tn*8+tk)*64 + lane)*8 + j.  FW1 first, FWhh second.
__global__ void prep_weights(const float* __restrict__ Wih,
                             const float* __restrict__ Whh,
                             unsigned short* __restrict__ fw){
  int id = blockIdx.x * 256 + threadIdx.x;     // 0 .. 2*FRAG_ELEMS-1
  int arr = (id >= FRAG_ELEMS);
  int r = arr ? (id - FRAG_ELEMS) : id;
  int j  = r & 7;
  int l  = (r >> 3) & 63;
  int tk = (r >> 9) & 7;
  int tn = r >> 12;                            // 0..47
  int c  = tn * 16 + (l & 15);                 // 0..767
  int d  = tk * 32 + ((l >> 4) << 3) + j;      // 0..255
  float v = arr ? Whh[c * 256 + d] : Wih[c * 512 + d];
  fw[id] = f2bf(v);
}

// r6 geometry+schedule (proven 124us): 256 blocks x 1024 thr, 4 waves/SIMD,
// unroll-4 tk, tk-skew, setprio, rcp/med3 gates, hoisted x-prefetch.
// HARD CONSTRAINT (3 spills measured): arch-VGPR cap is 64 here; no
// register prime/ring fits. This round's levers are register-neutral:
//  (1) raw barrier (lgkmcnt(0)+s_barrier, NO vmcnt drain) -- __syncthreads
//      was serializing all waves on wave0's out-store retire each step;
//  (2) cvt_pk bf16 packing for x-staging (32 VALU -> 4 per thread-step).
__global__ __launch_bounds__(NT, 4) void gru_main(
    const float* __restrict__ item, const float* __restrict__ user,
    const float* __restrict__ b_ih, const float* __restrict__ b_hh,
    const float* __restrict__ w_out, const float* __restrict__ b_out,
    const int* __restrict__ length, const unsigned short* __restrict__ ws,
    float* __restrict__ out)
{
  // A-fragment layout: elem (mt, tk, lane, j) at ((mt*8+tk)*64+lane)*8+j
  // double-buffered so one barrier/step suffices
  __shared__ unsigned short xfrag[2][2*8*64*8];   // 32 KB
  __shared__ unsigned short hfrag[2][2*8*64*8];   // 32 KB
  __shared__ float yp[3][16][2][4][4];            // 6 KB, triple-buffered

  const int tid  = threadIdx.x;
  const int lane = tid & 63;
  const int w    = tid >> 6;        // wave 0..15 == column group g
  const int col  = lane & 15;       // C-layout col
  const int q    = lane >> 4;       // quad
  const int nb   = blockIdx.x * ROWS;
  const int b    = nb / SS;         // one user per block (32 | 64)
  const int sk   = blockIdx.x & 7;  // tk read-order skew: decorrelate L2 bursts

  const short8* fw1 = (const short8*)ws;
  const short8* fwh = fw1 + (FRAG_ELEMS/8);

  // per-column constants (this thread owns output channel d for 8 rows)
  const int d    = w*16 + col;
  const float br_  = b_ih[d]       + b_hh[d];
  const float bz_  = b_ih[256 + d] + b_hh[256 + d];
  const float bin_ = b_ih[512 + d];
  const float bhn_ = b_hh[512 + d];
  const float wo_  = w_out[d];

  // weight fragment flat offsets (short8 units): frag(tn,tk) = fw[tn*512 + tk*64 + lane]
  const int wq0 = (w     )*512 + lane;   // gate r
  const int wq1 = (16 + w)*512 + lane;   // gate z
  const int wq2 = (32 + w)*512 + lane;   // gate n

  // h0 = user_embs[b, clip(length[b]-1,0)]; identical for all 32 rows
  int idx = length[b] - 1; if (idx < 0) idx = 0;
  const float u0 = user[((size_t)b*SS + idx)*DD + d];
  float h[2][4];
  #pragma unroll
  for (int mt = 0; mt < 2; ++mt)
    #pragma unroll
    for (int reg = 0; reg < 4; ++reg)
      h[mt][reg] = u0;

  // write h0 into hfrag[0] (A-fragment layout), owner-thread scatter
  const int tkk = d >> 5;
  const int slb = ((d >> 3) & 3) * 16;
  const int dj  = d & 7;
  {
    unsigned short hb = f2bf(u0);
    #pragma unroll
    for (int mt = 0; mt < 2; ++mt)
      #pragma unroll
      for (int reg = 0; reg < 4; ++reg)
        hfrag[0][((mt*8 + tkk)*64 + slb + q*4 + reg)*8 + dj] = hb;
  }

  // cooperative x-tile load: thread covers row = tid>>5, 8 d's at (tid&31)*8
  const int xrow = tid >> 5;        // 0..31
  const int xo   = tid & 31;        // which 8-wide d chunk
  const int xmt  = xrow >> 4;
  const int xtk  = xo >> 2;
  const int xsl  = (xo & 3)*16 + (xrow & 15);
  {
    const float4* p = (const float4*)(item + ((size_t)(nb + xrow)*KK + 0)*DD + xo*8);
    float4 a0 = p[0], a1 = p[1];
    uint4v t;
    t.x = cvtpk(a0.x, a0.y); t.y = cvtpk(a0.z, a0.w);
    t.z = cvtpk(a1.x, a1.y); t.w = cvtpk(a1.z, a1.w);
    *(uint4v*)&xfrag[0][((xmt*8 + xtk)*64 + xsl)*8] = t;
  }
  __syncthreads();

  const float bout = b_out[0];

#define MFMA16(A,Bv,C) __builtin_amdgcn_mfma_f32_16x16x32_bf16(A,Bv,C,0,0,0)

  for (int k = 0; k < KK; ++k){
    const int cb  = k & 1;
    const int nbf = cb ^ 1;

    // accumulators: [mt][kind]  kind: 0=r 1=z 2=i_n 3=h_n
    f32x4 acc[2][4];
    #pragma unroll
    for (int mt = 0; mt < 2; ++mt)
      #pragma unroll
      for (int kd = 0; kd < 4; ++kd){
        f32x4 z4 = {0.f, 0.f, 0.f, 0.f};
        acc[mt][kd] = z4;
      }

    // next x tile issued up-front: latency hides under the whole MFMA phase
    float4 xn0, xn1;
    if (k < KK-1){
      const float4* p = (const float4*)(item + ((size_t)(nb + xrow)*KK + (k+1))*DD + xo*8);
      xn0 = p[0]; xn1 = p[1];
    }

    // tk loop: unroll-4 lets the compiler pipeline next-iteration weight loads
    // under current MFMAs within the 64-arch-VGPR budget (no forced liveness).
    #pragma unroll 4
    for (int tk = 0; tk < 8; ++tk){
      const int tkv = (tk + sk) & 7;
      const int o_  = tkv * 64;
      short8 w1r = fw1[wq0+o_], w1z = fw1[wq1+o_], w1n = fw1[wq2+o_];
      short8 whr = fwh[wq0+o_], whz = fwh[wq1+o_], whn = fwh[wq2+o_];
      short8 ax0 = *(const short8*)&xfrag[cb][((    tkv)*64 + lane)*8];
      short8 ax1 = *(const short8*)&xfrag[cb][((8 + tkv)*64 + lane)*8];
      short8 ah0 = *(const short8*)&hfrag[cb][((    tkv)*64 + lane)*8];
      short8 ah1 = *(const short8*)&hfrag[cb][((8 + tkv)*64 + lane)*8];
      __builtin_amdgcn_s_setprio(1);
      acc[0][0] = MFMA16(ax0, w1r, acc[0][0]);
      acc[0][0] = MFMA16(ah0, whr, acc[0][0]);
      acc[0][1] = MFMA16(ax0, w1z, acc[0][1]);
      acc[0][1] = MFMA16(ah0, whz, acc[0][1]);
      acc[0][2] = MFMA16(ax0, w1n, acc[0][2]);
      acc[0][3] = MFMA16(ah0, whn, acc[0][3]);
      acc[1][0] = MFMA16(ax1, w1r, acc[1][0]);
      acc[1][0] = MFMA16(ah1, whr, acc[1][0]);
      acc[1][1] = MFMA16(ax1, w1z, acc[1][1]);
      acc[1][1] = MFMA16(ah1, whz, acc[1][1]);
      acc[1][2] = MFMA16(ax1, w1n, acc[1][2]);
      acc[1][3] = MFMA16(ah1, whn, acc[1][3]);
      __builtin_amdgcn_s_setprio(0);
    }

    // gates — entirely in-register (v_rcp + v_med3; verified same absmax)
    float ypl[2][4];
    #pragma unroll
    for (int mt = 0; mt < 2; ++mt)
      #pragma unroll
      for (int reg = 0; reg < 4; ++reg){
        float rp = acc[mt][0][reg] + br_;
        float zp = acc[mt][1][reg] + bz_;
        float r  = __builtin_amdgcn_rcpf(1.f + __expf(-rp));
        float z  = __builtin_amdgcn_rcpf(1.f + __expf(-zp));
        float np = acc[mt][2][reg] + bin_ + r*(acc[mt][3][reg] + bhn_);
        np = __builtin_amdgcn_fmed3f(np, -30.f, 30.f);
        float e  = __expf(2.f*np);
        float n  = 1.f - 2.f*__builtin_amdgcn_rcpf(e + 1.f);   // tanh(np)
        float hv = (1.f - z)*n + z*h[mt][reg];
        h[mt][reg] = hv;
        ypl[mt][reg] = hv * wo_;
      }

    // y partial: reduce across the 16 cols of this wave's group
    #pragma unroll
    for (int mt = 0; mt < 2; ++mt)
      #pragma unroll
      for (int reg = 0; reg < 4; ++reg){
        float p = ypl[mt][reg];
        p += __shfl_xor(p, 1);
        p += __shfl_xor(p, 2);
        p += __shfl_xor(p, 4);
        p += __shfl_xor(p, 8);
        if (col == 0) yp[k % 3][w][mt][q][reg] = p;
      }

    // write h' (bf16) into hfrag[nbf] for next step
    #pragma unroll
    for (int mt = 0; mt < 2; ++mt)
      #pragma unroll
      for (int reg = 0; reg < 4; ++reg)
        hfrag[nbf][((mt*8 + tkk)*64 + slb + q*4 + reg)*8 + dj] = f2bf(h[mt][reg]);

    // write next x tile into xfrag[nbf]
    if (k < KK-1){
      uint4v t;
      t.x = cvtpk(xn0.x, xn0.y); t.y = cvtpk(xn0.z, xn0.w);
      t.z = cvtpk(xn1.x, xn1.y); t.w = cvtpk(xn1.z, xn1.w);
      *(uint4v*)&xfrag[nbf][((xmt*8 + xtk)*64 + xsl)*8] = t;
    }

    // finalize y for step k-1 (yp[(k-1)%3] stable since previous barrier;
    // concurrent writes go to yp[k%3] which is a different buffer)
    if (k > 0 && tid < 32){
      float s = bout;
      #pragma unroll
      for (int ww = 0; ww < 16; ++ww)
        s += yp[(k-1) % 3][ww][tid >> 4][(tid >> 2) & 3][tid & 3];
      out[(size_t)(nb + tid)*KK + (k-1)] = s;
    }

    // raw barrier: order LDS only (lgkmcnt), do NOT drain vmcnt -- the only
    // in-flight vmem here is wave0's out-store (disjoint addresses per step;
    // kernel-end release handles final visibility). __syncthreads' implicit
    // vmcnt(0) was serializing all 16 waves on that store's HBM retire.
    asm volatile("s_waitcnt lgkmcnt(0)" ::: "memory");
    __builtin_amdgcn_s_barrier();
    __builtin_amdgcn_sched_barrier(0);
  }

  // finalize y for the last step
  if (tid < 32){
    float s = bout;
    #pragma unroll
    for (int ww = 0; ww < 16; ++ww)
      s += yp[(KK-1) % 3][ww][tid >> 4][(tid >> 2) & 3][tid & 3];
    out[(size_t)(nb + tid)*KK + (KK-1)] = s;
  }
}

extern "C" void kernel_launch(void* const* d_in, const int* in_sizes, int n_in,
                              void* d_out, int out_size, void* d_ws, size_t ws_size,
                              hipStream_t stream) {
  const float* item   = (const float*)d_in[0];
  const float* user   = (const float*)d_in[1];
  const float* W_ih   = (const float*)d_in[2];
  const float* W_hh   = (const float*)d_in[3];
  const float* b_ih   = (const float*)d_in[4];
  const float* b_hh   = (const float*)d_in[5];
  const float* w_out  = (const float*)d_in[6];
  const float* b_out  = (const float*)d_in[7];
  const int*   length = (const int*)d_in[8];
  unsigned short* ws  = (unsigned short*)d_ws;   // needs 768 KB
  float* out = (float*)d_out;

  hipLaunchKernelGGL(prep_weights, dim3((2*FRAG_ELEMS)/256), dim3(256), 0, stream,
                     W_ih, W_hh, ws);
  hipLaunchKernelGGL(gru_main, dim3(NBLK), dim3(NT), 0, stream,
                     item, user, b_ih, b_hh, w_out, b_out, length, ws, out);
}

// Round 9
// 215.065 us; speedup vs baseline: 2.0506x; 1.0246x over previous
//
#include <hip/hip_runtime.h>

#define BB 128
#define SS 64
#define KK 10
#define DD 256
#define NN (BB*SS)        // 8192 rows
#define ROWS 32           // rows per block
#define NBLK (NN/ROWS)    // 256 blocks = 1 per CU
#define NT 1024           // 16 waves per block -> 4 waves/SIMD

typedef __attribute__((ext_vector_type(8))) short short8;
typedef __attribute__((ext_vector_type(4))) float f32x4;
typedef __attribute__((ext_vector_type(4))) unsigned uint4v;

#define FRAG_ELEMS (48*8*64*8)   // 196608 bf16 values per weight matrix

__device__ __forceinline__ unsigned short f2bf(float f){
  union { float f; unsigned u; } v; v.f = f;
  unsigned r = (v.u + 0x7FFFu + ((v.u >> 16) & 1u)) >> 16;
  return (unsigned short)r;
}

// packed RNE f32->bf16 pair (no builtin on gfx950); same rounding as f2bf.
__device__ __forceinline__ unsigned cvtpk(float lo, float hi){
  unsigned r;
  asm("v_cvt_pk_bf16_f32 %0, %1, %2" : "=v"(r) : "v"(lo), "v"(hi));
  return r;
}

// Pre-swizzle W_ih[:, :D] and W_hh into bf16 MFMA B-fragment order:
// frag value at (tn, tk, lane, j) = W[c = tn*16 + (lane&15)][d = tk*32 + (lane>>4)*8 + j]
// stored flat at ((tn*8+tk)*64 + lane)*8 + j.  FW1 first, FWhh second.
__global__ void prep_weights(const float* __restrict__ Wih,
                             const float* __restrict__ Whh,
                             unsigned short* __restrict__ fw){
  int id = blockIdx.x * 256 + threadIdx.x;     // 0 .. 2*FRAG_ELEMS-1
  int arr = (id >= FRAG_ELEMS);
  int r = arr ? (id - FRAG_ELEMS) : id;
  int j  = r & 7;
  int l  = (r >> 3) & 63;
  int tk = (r >> 9) & 7;
  int tn = r >> 12;                            // 0..47
  int c  = tn * 16 + (l & 15);                 // 0..767
  int d  = tk * 32 + ((l >> 4) << 3) + j;      // 0..255
  float v = arr ? Whh[c * 256 + d] : Wih[c * 512 + d];
  fw[id] = f2bf(v);
}

// CHUNKED RESTRUCTURE (the x-half of the gates has no recurrence):
// per chunk c: (1) GI GEMM: gi[2 steps][mt][r,z,n] = x @ W1^T, reads fw1
// ONCE per chunk, 12 MFMA per 3 loads, no dependency, no barrier (gi is
// thread-private in C-layout -- same thread owns channel d in both phases);
// (2) two sequential steps reading ONLY fwh (3 loads/tk, half the chain),
// acc init = gi. Weight ingress/chunk: 1.15 MB vs 1.54; MFMA count conserved.
// Geometry fixed at 256x1024 (proven); budget 128 reg/wave unified; register
// peak ~110. Spill signature: FETCH >> 44 MB.
__global__ __launch_bounds__(NT, 4) void gru_main(
    const float* __restrict__ item, const float* __restrict__ user,
    const float* __restrict__ b_ih, const float* __restrict__ b_hh,
    const float* __restrict__ w_out, const float* __restrict__ b_out,
    const int* __restrict__ length, const unsigned short* __restrict__ ws,
    float* __restrict__ out)
{
  // A-fragment layout: elem (mt, tk, lane, j) at ((mt*8+tk)*64+lane)*8+j
  // xfrag[s] holds x for step 2c+s of the current chunk.
  __shared__ unsigned short xfrag[2][2*8*64*8];   // 32 KB
  __shared__ unsigned short hfrag[2][2*8*64*8];   // 32 KB
  __shared__ float yp[3][16][2][4][4];            // 6 KB, triple-buffered

  const int tid  = threadIdx.x;
  const int lane = tid & 63;
  const int w    = tid >> 6;        // wave 0..15 == column group g
  const int col  = lane & 15;       // C-layout col
  const int q    = lane >> 4;       // quad
  const int nb   = blockIdx.x * ROWS;
  const int b    = nb / SS;         // one user per block (32 | 64)
  const int sk   = blockIdx.x & 7;  // tk read-order skew: decorrelate L2 bursts

  const short8* fw1 = (const short8*)ws;
  const short8* fwh = fw1 + (FRAG_ELEMS/8);

  // per-column constants (this thread owns output channel d for 8 rows)
  const int d    = w*16 + col;
  const float br_  = b_ih[d]       + b_hh[d];
  const float bz_  = b_ih[256 + d] + b_hh[256 + d];
  const float bin_ = b_ih[512 + d];
  const float bhn_ = b_hh[512 + d];
  const float wo_  = w_out[d];

  // weight fragment flat offsets (short8 units): frag(tn,tk) = fw[tn*512 + tk*64 + lane]
  const int wq0 = (w     )*512 + lane;   // gate r
  const int wq1 = (16 + w)*512 + lane;   // gate z
  const int wq2 = (32 + w)*512 + lane;   // gate n

  // h0 = user_embs[b, clip(length[b]-1,0)]; identical for all 32 rows
  int idx = length[b] - 1; if (idx < 0) idx = 0;
  const float u0 = user[((size_t)b*SS + idx)*DD + d];
  float h[2][4];
  #pragma unroll
  for (int mt = 0; mt < 2; ++mt)
    #pragma unroll
    for (int reg = 0; reg < 4; ++reg)
      h[mt][reg] = u0;

  // write h0 into hfrag[0] (A-fragment layout), owner-thread scatter
  const int tkk = d >> 5;
  const int slb = ((d >> 3) & 3) * 16;
  const int dj  = d & 7;
  {
    unsigned short hb = f2bf(u0);
    #pragma unroll
    for (int mt = 0; mt < 2; ++mt)
      #pragma unroll
      for (int reg = 0; reg < 4; ++reg)
        hfrag[0][((mt*8 + tkk)*64 + slb + q*4 + reg)*8 + dj] = hb;
  }

  // cooperative x staging for steps 0 and 1
  const int xrow = tid >> 5;        // 0..31
  const int xo   = tid & 31;        // which 8-wide d chunk
  const int xmt  = xrow >> 4;
  const int xtk  = xo >> 2;
  const int xsl  = (xo & 3)*16 + (xrow & 15);
  #pragma unroll
  for (int s = 0; s < 2; ++s){
    const float4* p = (const float4*)(item + ((size_t)(nb + xrow)*KK + s)*DD + xo*8);
    float4 a0 = p[0], a1 = p[1];
    uint4v t;
    t.x = cvtpk(a0.x, a0.y); t.y = cvtpk(a0.z, a0.w);
    t.z = cvtpk(a1.x, a1.y); t.w = cvtpk(a1.z, a1.w);
    *(uint4v*)&xfrag[s][((xmt*8 + xtk)*64 + xsl)*8] = t;
  }
  __syncthreads();

  const float bout = b_out[0];

#define MFMA16(A,Bv,C) __builtin_amdgcn_mfma_f32_16x16x32_bf16(A,Bv,C,0,0,0)

  for (int c = 0; c < KK/2; ++c){
    // ---------- GI GEMM: x-part of gates for steps 2c and 2c+1 ----------
    f32x4 gi[2][2][3];   // [step][mt][r,z,n]
    #pragma unroll
    for (int s = 0; s < 2; ++s)
      #pragma unroll
      for (int mt = 0; mt < 2; ++mt)
        #pragma unroll
        for (int g = 0; g < 3; ++g){
          f32x4 z4 = {0.f, 0.f, 0.f, 0.f};
          gi[s][mt][g] = z4;
        }

    #pragma unroll 2
    for (int tk = 0; tk < 8; ++tk){
      const int tkv = (tk + sk) & 7;
      const int o_  = tkv * 64;
      short8 w1r = fw1[wq0+o_], w1z = fw1[wq1+o_], w1n = fw1[wq2+o_];
      short8 a00 = *(const short8*)&xfrag[0][((    tkv)*64 + lane)*8];
      short8 a01 = *(const short8*)&xfrag[0][((8 + tkv)*64 + lane)*8];
      short8 a10 = *(const short8*)&xfrag[1][((    tkv)*64 + lane)*8];
      short8 a11 = *(const short8*)&xfrag[1][((8 + tkv)*64 + lane)*8];
      __builtin_amdgcn_s_setprio(1);
      gi[0][0][0] = MFMA16(a00, w1r, gi[0][0][0]);
      gi[0][0][1] = MFMA16(a00, w1z, gi[0][0][1]);
      gi[0][0][2] = MFMA16(a00, w1n, gi[0][0][2]);
      gi[0][1][0] = MFMA16(a01, w1r, gi[0][1][0]);
      gi[0][1][1] = MFMA16(a01, w1z, gi[0][1][1]);
      gi[0][1][2] = MFMA16(a01, w1n, gi[0][1][2]);
      gi[1][0][0] = MFMA16(a10, w1r, gi[1][0][0]);
      gi[1][0][1] = MFMA16(a10, w1z, gi[1][0][1]);
      gi[1][0][2] = MFMA16(a10, w1n, gi[1][0][2]);
      gi[1][1][0] = MFMA16(a11, w1r, gi[1][1][0]);
      gi[1][1][1] = MFMA16(a11, w1z, gi[1][1][1]);
      gi[1][1][2] = MFMA16(a11, w1n, gi[1][1][2]);
      __builtin_amdgcn_s_setprio(0);
    }
    // no barrier: gi is thread-private; xfrag buffers not written until
    // step 2c+1, which is after barrier B(2c) -> all waves done reading.

    // ---------- two sequential steps (h-recurrence, fwh only) ----------
    #pragma unroll
    for (int s = 0; s < 2; ++s){
      const int k   = 2*c + s;
      const int cb  = s;          // k&1 == s (chunk-aligned)
      const int nbf = s ^ 1;

      // acc: [mt][0]=r (init gi), [1]=z (init gi), [2]=h_n (init 0)
      f32x4 acc[2][3];
      #pragma unroll
      for (int mt = 0; mt < 2; ++mt){
        acc[mt][0] = gi[s][mt][0];
        acc[mt][1] = gi[s][mt][1];
        f32x4 z4 = {0.f, 0.f, 0.f, 0.f};
        acc[mt][2] = z4;
      }

      // during step 2c+1: issue next chunk's x loads (both steps) up-front
      float4 xa0, xa1, xb0, xb1;
      if (s == 1 && c < KK/2-1){
        const float4* pA = (const float4*)(item + ((size_t)(nb + xrow)*KK + (2*c+2))*DD + xo*8);
        const float4* pB = (const float4*)(item + ((size_t)(nb + xrow)*KK + (2*c+3))*DD + xo*8);
        xa0 = pA[0]; xa1 = pA[1]; xb0 = pB[0]; xb1 = pB[1];
      }

      #pragma unroll 4
      for (int tk = 0; tk < 8; ++tk){
        const int tkv = (tk + sk) & 7;
        const int o_  = tkv * 64;
        short8 whr = fwh[wq0+o_], whz = fwh[wq1+o_], whn = fwh[wq2+o_];
        short8 ah0 = *(const short8*)&hfrag[cb][((    tkv)*64 + lane)*8];
        short8 ah1 = *(const short8*)&hfrag[cb][((8 + tkv)*64 + lane)*8];
        __builtin_amdgcn_s_setprio(1);
        acc[0][0] = MFMA16(ah0, whr, acc[0][0]);
        acc[0][1] = MFMA16(ah0, whz, acc[0][1]);
        acc[0][2] = MFMA16(ah0, whn, acc[0][2]);
        acc[1][0] = MFMA16(ah1, whr, acc[1][0]);
        acc[1][1] = MFMA16(ah1, whz, acc[1][1]);
        acc[1][2] = MFMA16(ah1, whn, acc[1][2]);
        __builtin_amdgcn_s_setprio(0);
      }

      // gates — in-register (v_rcp + v_med3; verified same absmax)
      float ypl[2][4];
      #pragma unroll
      for (int mt = 0; mt < 2; ++mt)
        #pragma unroll
        for (int reg = 0; reg < 4; ++reg){
          float rp = acc[mt][0][reg] + br_;
          float zp = acc[mt][1][reg] + bz_;
          float r  = __builtin_amdgcn_rcpf(1.f + __expf(-rp));
          float z  = __builtin_amdgcn_rcpf(1.f + __expf(-zp));
          float np = gi[s][mt][2][reg] + bin_ + r*(acc[mt][2][reg] + bhn_);
          np = __builtin_amdgcn_fmed3f(np, -30.f, 30.f);
          float e  = __expf(2.f*np);
          float n  = 1.f - 2.f*__builtin_amdgcn_rcpf(e + 1.f);   // tanh(np)
          float hv = (1.f - z)*n + z*h[mt][reg];
          h[mt][reg] = hv;
          ypl[mt][reg] = hv * wo_;
        }

      // y partial: reduce across the 16 cols of this wave's group
      #pragma unroll
      for (int mt = 0; mt < 2; ++mt)
        #pragma unroll
        for (int reg = 0; reg < 4; ++reg){
          float p = ypl[mt][reg];
          p += __shfl_xor(p, 1);
          p += __shfl_xor(p, 2);
          p += __shfl_xor(p, 4);
          p += __shfl_xor(p, 8);
          if (col == 0) yp[k % 3][w][mt][q][reg] = p;
        }

      // write h' (bf16) into hfrag[nbf] for next step
      #pragma unroll
      for (int mt = 0; mt < 2; ++mt)
        #pragma unroll
        for (int reg = 0; reg < 4; ++reg)
          hfrag[nbf][((mt*8 + tkk)*64 + slb + q*4 + reg)*8 + dj] = f2bf(h[mt][reg]);

      // stage next chunk's x into xfrag[0..1] (safe: past barrier B(2c),
      // so every wave has finished this chunk's GI GEMM reads)
      if (s == 1 && c < KK/2-1){
        uint4v t;
        t.x = cvtpk(xa0.x, xa0.y); t.y = cvtpk(xa0.z, xa0.w);
        t.z = cvtpk(xa1.x, xa1.y); t.w = cvtpk(xa1.z, xa1.w);
        *(uint4v*)&xfrag[0][((xmt*8 + xtk)*64 + xsl)*8] = t;
        t.x = cvtpk(xb0.x, xb0.y); t.y = cvtpk(xb0.z, xb0.w);
        t.z = cvtpk(xb1.x, xb1.y); t.w = cvtpk(xb1.z, xb1.w);
        *(uint4v*)&xfrag[1][((xmt*8 + xtk)*64 + xsl)*8] = t;
      }

      // finalize y for step k-1 (yp[(k-1)%3] stable since previous barrier)
      if (k > 0 && tid < 32){
        float sacc = bout;
        #pragma unroll
        for (int ww = 0; ww < 16; ++ww)
          sacc += yp[(k-1) % 3][ww][tid >> 4][(tid >> 2) & 3][tid & 3];
        out[(size_t)(nb + tid)*KK + (k-1)] = sacc;
      }

      // raw barrier: order LDS only; do NOT drain vmcnt (out-store + x loads
      // may stay in flight; disjoint addresses, kernel-end release suffices)
      asm volatile("s_waitcnt lgkmcnt(0)" ::: "memory");
      __builtin_amdgcn_s_barrier();
      __builtin_amdgcn_sched_barrier(0);
    }
  }

  // finalize y for the last step
  if (tid < 32){
    float s = bout;
    #pragma unroll
    for (int ww = 0; ww < 16; ++ww)
      s += yp[(KK-1) % 3][ww][tid >> 4][(tid >> 2) & 3][tid & 3];
    out[(size_t)(nb + tid)*KK + (KK-1)] = s;
  }
}

extern "C" void kernel_launch(void* const* d_in, const int* in_sizes, int n_in,
                              void* d_out, int out_size, void* d_ws, size_t ws_size,
                              hipStream_t stream) {
  const float* item   = (const float*)d_in[0];
  const float* user   = (const float*)d_in[1];
  const float* W_ih   = (const float*)d_in[2];
  const float* W_hh   = (const float*)d_in[3];
  const float* b_ih   = (const float*)d_in[4];
  const float* b_hh   = (const float*)d_in[5];
  const float* w_out  = (const float*)d_in[6];
  const float* b_out  = (const float*)d_in[7];
  const int*   length = (const int*)d_in[8];
  unsigned short* ws  = (unsigned short*)d_ws;   // needs 768 KB
  float* out = (float*)d_out;

  hipLaunchKernelGGL(prep_weights, dim3((2*FRAG_ELEMS)/256), dim3(256), 0, stream,
                     W_ih, W_hh, ws);
  hipLaunchKernelGGL(gru_main, dim3(NBLK), dim3(NT), 0, stream,
                     item, user, b_ih, b_hh, w_out, b_out, length, ws, out);
}